// Round 1
// baseline (754.347 us; speedup 1.0000x reference)
//
#include <hip/hip_runtime.h>
#include <hip/hip_bf16.h>
#include <math.h>

#define N_NODES 100000
#define IN_F 256
#define HID 128
#define NCLS 40

typedef __attribute__((ext_vector_type(8))) short short8;
typedef __attribute__((ext_vector_type(4))) float f32x4;

__device__ __forceinline__ short f2bf(float f){
  union { float f; unsigned u; } x; x.f = f;
  unsigned r = (x.u + 0x7fffu + ((x.u >> 16) & 1u)) >> 16;
  return (short)r;
}
__device__ __forceinline__ float bf2f(unsigned short u){
  union { unsigned u; float f; } x; x.u = ((unsigned)u) << 16;
  return x.f;
}

// ---------------- CSR build ----------------
__global__ void k_zero(int* p, int n){
  int i = blockIdx.x*blockDim.x + threadIdx.x;
  if(i < n) p[i] = 0;
}

__global__ void k_count(const int* __restrict__ dst, int* __restrict__ counts, int e){
  int i = blockIdx.x*blockDim.x + threadIdx.x;
  if(i < e) atomicAdd(&counts[dst[i]], 1);
}

#define SCAN_BLK 512
__global__ void k_scanA(const int* __restrict__ counts, int* __restrict__ offs,
                        int* __restrict__ partials, int n){
  __shared__ int s[SCAN_BLK];
  const int t = threadIdx.x;
  const int i = blockIdx.x*SCAN_BLK + t;
  int v = (i < n) ? counts[i] : 0;
  s[t] = v; __syncthreads();
  for(int d = 1; d < SCAN_BLK; d <<= 1){
    int add = (t >= d) ? s[t-d] : 0;
    __syncthreads();
    s[t] += add;
    __syncthreads();
  }
  if(i < n) offs[i] = s[t] - v;                 // block-local exclusive
  if(t == SCAN_BLK-1) partials[blockIdx.x] = s[t];
}

__global__ void k_scanB(int* partials, int n){
  __shared__ int s[256];
  const int t = threadIdx.x;
  int v = (t < n) ? partials[t] : 0;
  s[t] = v; __syncthreads();
  for(int d = 1; d < 256; d <<= 1){
    int add = (t >= d) ? s[t-d] : 0;
    __syncthreads();
    s[t] += add;
    __syncthreads();
  }
  if(t < n) partials[t] = s[t] - v;             // exclusive
}

__global__ void k_scanC(int* __restrict__ offs, const int* __restrict__ partials,
                        int* __restrict__ cursor, int n){
  int i = blockIdx.x*blockDim.x + threadIdx.x;
  if(i < n){
    int v = offs[i] + partials[blockIdx.x];
    offs[i] = v;
    cursor[i] = v;
  }
}

__global__ void k_scatter(const int* __restrict__ src, const int* __restrict__ dst,
                          int* __restrict__ cursor, int* __restrict__ esrc, int e){
  int i = blockIdx.x*blockDim.x + threadIdx.x;
  if(i < e){
    int d = dst[i];
    int pos = atomicAdd(&cursor[d], 1);
    esrc[pos] = src[i];
  }
}

// ---------------- pre GEMM: h0 = x @ W_pre + b_pre  (f32 in, bf16 out) ----------------
__global__ __launch_bounds__(256) void k_gemm_pre(
    const float* __restrict__ x, const float* __restrict__ W,
    const float* __restrict__ b, unsigned short* __restrict__ out)
{
  __shared__ short wlds[8][8][64][8];   // [ct][kb][lane][j] : B-frag layout, 64 KiB
  const int t = threadIdx.x;
  for(int idx = t; idx < 8*8*64; idx += 256){
    const int ct = idx >> 9, kb = (idx >> 6) & 7, l = idx & 63;
    const int col = ct*16 + (l & 15);
    const int kbase = kb*32 + (l >> 4)*8;
    short8 v;
    #pragma unroll
    for(int j = 0; j < 8; j++) v[j] = f2bf(W[(size_t)(kbase+j)*HID + col]);
    *reinterpret_cast<short8*>(&wlds[ct][kb][l][0]) = v;
  }
  __syncthreads();
  const int wave = t >> 6, lane = t & 63;
  const int r_in = lane & 15, kg = lane >> 4;
  for(int tile = blockIdx.x*4 + wave; tile < N_NODES/16; tile += gridDim.x*4){
    const int row0 = tile*16;
    f32x4 acc[8];
    #pragma unroll
    for(int ct = 0; ct < 8; ct++) acc[ct] = (f32x4){0.f,0.f,0.f,0.f};
    #pragma unroll
    for(int kb = 0; kb < 8; kb++){
      const float* xp = x + (size_t)(row0 + r_in)*IN_F + kb*32 + kg*8;
      float4 xa = *reinterpret_cast<const float4*>(xp);
      float4 xb = *reinterpret_cast<const float4*>(xp + 4);
      short8 a;
      a[0]=f2bf(xa.x); a[1]=f2bf(xa.y); a[2]=f2bf(xa.z); a[3]=f2bf(xa.w);
      a[4]=f2bf(xb.x); a[5]=f2bf(xb.y); a[6]=f2bf(xb.z); a[7]=f2bf(xb.w);
      #pragma unroll
      for(int ct = 0; ct < 8; ct++){
        short8 bb = *reinterpret_cast<const short8*>(&wlds[ct][kb][lane][0]);
        acc[ct] = __builtin_amdgcn_mfma_f32_16x16x32_bf16(a, bb, acc[ct], 0, 0, 0);
      }
    }
    #pragma unroll
    for(int ct = 0; ct < 8; ct++){
      const int col = ct*16 + r_in;
      const float bias = b[col];
      #pragma unroll
      for(int i = 0; i < 4; i++){
        const int row = row0 + kg*4 + i;
        out[(size_t)row*HID + col] = (unsigned short)f2bf(acc[ct][i] + bias);
      }
    }
  }
}

// ------- sage GEMM: out = relu(mean @ Wl + bl + h @ Wr)  (bf16 in/out) -------
__global__ __launch_bounds__(256) void k_gemm_sage(
    const unsigned short* __restrict__ mean, const unsigned short* __restrict__ h,
    const float* __restrict__ Wl, const float* __restrict__ bl,
    const float* __restrict__ Wr, unsigned short* __restrict__ out)
{
  __shared__ short wlds[8][8][64][8];   // kb 0..3 -> Wl, 4..7 -> Wr
  const int t = threadIdx.x;
  for(int idx = t; idx < 8*8*64; idx += 256){
    const int ct = idx >> 9, kb = (idx >> 6) & 7, l = idx & 63;
    const float* Wsrc = (kb < 4) ? Wl : Wr;
    const int col = ct*16 + (l & 15);
    const int kbase = (kb & 3)*32 + (l >> 4)*8;
    short8 v;
    #pragma unroll
    for(int j = 0; j < 8; j++) v[j] = f2bf(Wsrc[(size_t)(kbase+j)*HID + col]);
    *reinterpret_cast<short8*>(&wlds[ct][kb][l][0]) = v;
  }
  __syncthreads();
  const int wave = t >> 6, lane = t & 63;
  const int r_in = lane & 15, kg = lane >> 4;
  for(int tile = blockIdx.x*4 + wave; tile < N_NODES/16; tile += gridDim.x*4){
    const int row0 = tile*16;
    f32x4 acc[8];
    #pragma unroll
    for(int ct = 0; ct < 8; ct++) acc[ct] = (f32x4){0.f,0.f,0.f,0.f};
    #pragma unroll
    for(int kb = 0; kb < 8; kb++){
      const unsigned short* in = (kb < 4) ? mean : h;
      const int koff = (kb & 3)*32 + kg*8;
      short8 a = *reinterpret_cast<const short8*>(in + (size_t)(row0 + r_in)*HID + koff);
      #pragma unroll
      for(int ct = 0; ct < 8; ct++){
        short8 bb = *reinterpret_cast<const short8*>(&wlds[ct][kb][lane][0]);
        acc[ct] = __builtin_amdgcn_mfma_f32_16x16x32_bf16(a, bb, acc[ct], 0, 0, 0);
      }
    }
    #pragma unroll
    for(int ct = 0; ct < 8; ct++){
      const int col = ct*16 + r_in;
      const float bias = bl[col];
      #pragma unroll
      for(int i = 0; i < 4; i++){
        const int row = row0 + kg*4 + i;
        float v = fmaxf(acc[ct][i] + bias, 0.f);
        out[(size_t)row*HID + col] = (unsigned short)f2bf(v);
      }
    }
  }
}

// ---------------- CSR mean aggregation (bf16 h -> bf16 mean) ----------------
__global__ __launch_bounds__(256) void k_aggregate(
    const unsigned short* __restrict__ h, const int* __restrict__ offs,
    const int* __restrict__ counts, const int* __restrict__ esrc,
    unsigned short* __restrict__ mean)
{
  const int node = blockIdx.x*4 + (threadIdx.x >> 6);
  const int lane = threadIdx.x & 63;
  if(node >= N_NODES) return;
  const int beg = offs[node];
  const int deg = counts[node];
  const unsigned* hp = (const unsigned*)h;
  float a0 = 0.f, a1 = 0.f;
  for(int e = 0; e < deg; e++){
    const int s = esrc[beg + e];
    const unsigned v = hp[(size_t)s*64 + lane];
    a0 += bf2f((unsigned short)(v & 0xffffu));
    a1 += bf2f((unsigned short)(v >> 16));
  }
  const float inv = (deg > 0) ? (1.0f/(float)deg) : 0.f;
  a0 *= inv; a1 *= inv;
  unsigned o = ((unsigned)(unsigned short)f2bf(a1) << 16) | (unsigned)(unsigned short)f2bf(a0);
  ((unsigned*)mean)[(size_t)node*64 + lane] = o;
}

// ---------------- post: log_softmax(h @ W_post + b_post) ----------------
__global__ __launch_bounds__(256) void k_post(
    const unsigned short* __restrict__ h, const float* __restrict__ W,
    const float* __restrict__ b, float* __restrict__ out)
{
  __shared__ float wl[HID*NCLS];
  __shared__ float hs[4][HID];
  for(int i = threadIdx.x; i < HID*NCLS; i += 256) wl[i] = W[i];
  __syncthreads();
  const int wave = threadIdx.x >> 6, lane = threadIdx.x & 63;
  for(int row = blockIdx.x*4 + wave; row < N_NODES; row += gridDim.x*4){
    if(lane < 16){
      short8 v = *reinterpret_cast<const short8*>(h + (size_t)row*HID + lane*8);
      #pragma unroll
      for(int j = 0; j < 8; j++) hs[wave][lane*8 + j] = bf2f((unsigned short)v[j]);
    }
    __syncthreads();   // uniform trip counts: N % 4 == 0
    float acc;
    if(lane < NCLS){
      float s = b[lane];
      #pragma unroll 8
      for(int k = 0; k < HID; k++) s += hs[wave][k]*wl[k*NCLS + lane];
      acc = s;
    } else acc = -1e30f;
    float m = acc;
    #pragma unroll
    for(int o = 32; o > 0; o >>= 1) m = fmaxf(m, __shfl_xor(m, o));
    float ex = (lane < NCLS) ? expf(acc - m) : 0.f;
    float ssum = ex;
    #pragma unroll
    for(int o = 32; o > 0; o >>= 1) ssum += __shfl_xor(ssum, o);
    const float ls = logf(ssum);
    if(lane < NCLS) out[(size_t)row*NCLS + lane] = acc - m - ls;
    __syncthreads();
  }
}

extern "C" void kernel_launch(void* const* d_in, const int* in_sizes, int n_in,
                              void* d_out, int out_size, void* d_ws, size_t ws_size,
                              hipStream_t stream)
{
  const float* x      = (const float*)d_in[0];
  const int*   ei     = (const int*)  d_in[1];
  const float* W_pre  = (const float*)d_in[2];
  const float* b_pre  = (const float*)d_in[3];
  const float* Wl0    = (const float*)d_in[4];
  const float* bl0    = (const float*)d_in[5];
  const float* Wr0    = (const float*)d_in[6];
  const float* Wl1    = (const float*)d_in[7];
  const float* bl1    = (const float*)d_in[8];
  const float* Wr1    = (const float*)d_in[9];
  const float* W_post = (const float*)d_in[10];
  const float* b_post = (const float*)d_in[11];
  float* out = (float*)d_out;

  const int E = in_sizes[1] / 2;
  const int* src = ei;
  const int* dst = ei + E;

  char* ws = (char*)d_ws;
  size_t off = 0;
  auto alloc = [&](size_t bytes)->void*{
    void* p = ws + off;
    off += (bytes + 255) & ~(size_t)255;
    return p;
  };
  unsigned short* hA = (unsigned short*)alloc((size_t)N_NODES*HID*2);
  unsigned short* hB = (unsigned short*)alloc((size_t)N_NODES*HID*2);
  unsigned short* hM = (unsigned short*)alloc((size_t)N_NODES*HID*2);
  int* counts   = (int*)alloc((size_t)N_NODES*4);
  int* offs     = (int*)alloc((size_t)N_NODES*4);
  int* cursor   = (int*)alloc((size_t)N_NODES*4);
  int* esrc     = (int*)alloc((size_t)E*4);
  int* partials = (int*)alloc(1024);

  // ---- CSR build (amortized over both layers) ----
  k_zero<<<(N_NODES+255)/256, 256, 0, stream>>>(counts, N_NODES);
  k_count<<<(E+255)/256, 256, 0, stream>>>(dst, counts, E);
  const int nb = (N_NODES + SCAN_BLK - 1) / SCAN_BLK;   // 196
  k_scanA<<<nb, SCAN_BLK, 0, stream>>>(counts, offs, partials, N_NODES);
  k_scanB<<<1, 256, 0, stream>>>(partials, nb);
  k_scanC<<<nb, SCAN_BLK, 0, stream>>>(offs, partials, cursor, N_NODES);
  k_scatter<<<(E+255)/256, 256, 0, stream>>>(src, dst, cursor, esrc, E);

  // ---- pre linear ----
  k_gemm_pre<<<1563, 256, 0, stream>>>(x, W_pre, b_pre, hA);

  // ---- SAGE layer 0 ----
  k_aggregate<<<N_NODES/4, 256, 0, stream>>>(hA, offs, counts, esrc, hM);
  k_gemm_sage<<<1563, 256, 0, stream>>>(hM, hA, Wl0, bl0, Wr0, hB);

  // ---- SAGE layer 1 ----
  k_aggregate<<<N_NODES/4, 256, 0, stream>>>(hB, offs, counts, esrc, hM);
  k_gemm_sage<<<1563, 256, 0, stream>>>(hM, hB, Wl1, bl1, Wr1, hA);

  // ---- post linear + log_softmax ----
  k_post<<<6250, 256, 0, stream>>>(hA, W_post, b_post, out);
}

// Round 2
// 573.585 us; speedup vs baseline: 1.3151x; 1.3151x over previous
//
#include <hip/hip_runtime.h>
#include <hip/hip_bf16.h>
#include <math.h>

#define N_NODES 100000
#define IN_F 256
#define HID 128
#define NCLS 40

typedef __attribute__((ext_vector_type(8))) short short8;
typedef __attribute__((ext_vector_type(4))) float f32x4;

__device__ __forceinline__ short f2bf(float f){
  union { float f; unsigned u; } x; x.f = f;
  unsigned r = (x.u + 0x7fffu + ((x.u >> 16) & 1u)) >> 16;
  return (short)r;
}
__device__ __forceinline__ float bf2f(unsigned short u){
  union { unsigned u; float f; } x; x.u = ((unsigned)u) << 16;
  return x.f;
}

// ---------------- CSR build ----------------
__global__ void k_zero(int* p, int n){
  int i = blockIdx.x*blockDim.x + threadIdx.x;
  if(i < n) p[i] = 0;
}

__global__ void k_count(const int* __restrict__ dst, int* __restrict__ counts, int e){
  int i = blockIdx.x*blockDim.x + threadIdx.x;
  if(i < e) atomicAdd(&counts[dst[i]], 1);
}

#define SCAN_BLK 512
__global__ void k_scanA(const int* __restrict__ counts, int* __restrict__ offs,
                        int* __restrict__ partials, int n){
  __shared__ int s[SCAN_BLK];
  const int t = threadIdx.x;
  const int i = blockIdx.x*SCAN_BLK + t;
  int v = (i < n) ? counts[i] : 0;
  s[t] = v; __syncthreads();
  for(int d = 1; d < SCAN_BLK; d <<= 1){
    int add = (t >= d) ? s[t-d] : 0;
    __syncthreads();
    s[t] += add;
    __syncthreads();
  }
  if(i < n) offs[i] = s[t] - v;                 // block-local exclusive
  if(t == SCAN_BLK-1) partials[blockIdx.x] = s[t];
}

__global__ void k_scanB(int* partials, int n){
  __shared__ int s[256];
  const int t = threadIdx.x;
  int v = (t < n) ? partials[t] : 0;
  s[t] = v; __syncthreads();
  for(int d = 1; d < 256; d <<= 1){
    int add = (t >= d) ? s[t-d] : 0;
    __syncthreads();
    s[t] += add;
    __syncthreads();
  }
  if(t < n) partials[t] = s[t] - v;             // exclusive
}

__global__ void k_scanC(int* __restrict__ offs, const int* __restrict__ partials,
                        int* __restrict__ cursor, int n){
  int i = blockIdx.x*blockDim.x + threadIdx.x;
  if(i < n){
    int v = offs[i] + partials[blockIdx.x];
    offs[i] = v;
    cursor[i] = v;
  }
}

__global__ void k_scatter(const int* __restrict__ src, const int* __restrict__ dst,
                          int* __restrict__ cursor, int* __restrict__ esrc, int e){
  int i = blockIdx.x*blockDim.x + threadIdx.x;
  if(i < e){
    int d = dst[i];
    int pos = atomicAdd(&cursor[d], 1);
    esrc[pos] = src[i];
  }
}

// ---------------- pre GEMM: h0 = x @ W_pre + b_pre  (f32 in, bf16 out) ----------------
__global__ __launch_bounds__(256) void k_gemm_pre(
    const float* __restrict__ x, const float* __restrict__ W,
    const float* __restrict__ b, unsigned short* __restrict__ out)
{
  __shared__ short wlds[8][8][64][8];   // [ct][kb][lane][j] : B-frag layout, 64 KiB
  const int t = threadIdx.x;
  for(int idx = t; idx < 8*8*64; idx += 256){
    const int ct = idx >> 9, kb = (idx >> 6) & 7, l = idx & 63;
    const int col = ct*16 + (l & 15);
    const int kbase = kb*32 + (l >> 4)*8;
    short8 v;
    #pragma unroll
    for(int j = 0; j < 8; j++) v[j] = f2bf(W[(size_t)(kbase+j)*HID + col]);
    *reinterpret_cast<short8*>(&wlds[ct][kb][l][0]) = v;
  }
  __syncthreads();
  const int wave = t >> 6, lane = t & 63;
  const int r_in = lane & 15, kg = lane >> 4;
  for(int tile = blockIdx.x*4 + wave; tile < N_NODES/16; tile += gridDim.x*4){
    const int row0 = tile*16;
    f32x4 acc[8];
    #pragma unroll
    for(int ct = 0; ct < 8; ct++) acc[ct] = (f32x4){0.f,0.f,0.f,0.f};
    #pragma unroll
    for(int kb = 0; kb < 8; kb++){
      const float* xp = x + (size_t)(row0 + r_in)*IN_F + kb*32 + kg*8;
      float4 xa = *reinterpret_cast<const float4*>(xp);
      float4 xb = *reinterpret_cast<const float4*>(xp + 4);
      short8 a;
      a[0]=f2bf(xa.x); a[1]=f2bf(xa.y); a[2]=f2bf(xa.z); a[3]=f2bf(xa.w);
      a[4]=f2bf(xb.x); a[5]=f2bf(xb.y); a[6]=f2bf(xb.z); a[7]=f2bf(xb.w);
      #pragma unroll
      for(int ct = 0; ct < 8; ct++){
        short8 bb = *reinterpret_cast<const short8*>(&wlds[ct][kb][lane][0]);
        acc[ct] = __builtin_amdgcn_mfma_f32_16x16x32_bf16(a, bb, acc[ct], 0, 0, 0);
      }
    }
    #pragma unroll
    for(int ct = 0; ct < 8; ct++){
      const int col = ct*16 + r_in;
      const float bias = b[col];
      #pragma unroll
      for(int i = 0; i < 4; i++){
        const int row = row0 + kg*4 + i;
        out[(size_t)row*HID + col] = (unsigned short)f2bf(acc[ct][i] + bias);
      }
    }
  }
}

// ------- sage GEMM: out = relu(mean @ Wl + bl + h @ Wr)  (bf16 in/out) -------
__global__ __launch_bounds__(256) void k_gemm_sage(
    const unsigned short* __restrict__ mean, const unsigned short* __restrict__ h,
    const float* __restrict__ Wl, const float* __restrict__ bl,
    const float* __restrict__ Wr, unsigned short* __restrict__ out)
{
  __shared__ short wlds[8][8][64][8];   // kb 0..3 -> Wl, 4..7 -> Wr
  const int t = threadIdx.x;
  for(int idx = t; idx < 8*8*64; idx += 256){
    const int ct = idx >> 9, kb = (idx >> 6) & 7, l = idx & 63;
    const float* Wsrc = (kb < 4) ? Wl : Wr;
    const int col = ct*16 + (l & 15);
    const int kbase = (kb & 3)*32 + (l >> 4)*8;
    short8 v;
    #pragma unroll
    for(int j = 0; j < 8; j++) v[j] = f2bf(Wsrc[(size_t)(kbase+j)*HID + col]);
    *reinterpret_cast<short8*>(&wlds[ct][kb][l][0]) = v;
  }
  __syncthreads();
  const int wave = t >> 6, lane = t & 63;
  const int r_in = lane & 15, kg = lane >> 4;
  for(int tile = blockIdx.x*4 + wave; tile < N_NODES/16; tile += gridDim.x*4){
    const int row0 = tile*16;
    f32x4 acc[8];
    #pragma unroll
    for(int ct = 0; ct < 8; ct++) acc[ct] = (f32x4){0.f,0.f,0.f,0.f};
    #pragma unroll
    for(int kb = 0; kb < 8; kb++){
      const unsigned short* in = (kb < 4) ? mean : h;
      const int koff = (kb & 3)*32 + kg*8;
      short8 a = *reinterpret_cast<const short8*>(in + (size_t)(row0 + r_in)*HID + koff);
      #pragma unroll
      for(int ct = 0; ct < 8; ct++){
        short8 bb = *reinterpret_cast<const short8*>(&wlds[ct][kb][lane][0]);
        acc[ct] = __builtin_amdgcn_mfma_f32_16x16x32_bf16(a, bb, acc[ct], 0, 0, 0);
      }
    }
    #pragma unroll
    for(int ct = 0; ct < 8; ct++){
      const int col = ct*16 + r_in;
      const float bias = bl[col];
      #pragma unroll
      for(int i = 0; i < 4; i++){
        const int row = row0 + kg*4 + i;
        float v = fmaxf(acc[ct][i] + bias, 0.f);
        out[(size_t)row*HID + col] = (unsigned short)f2bf(v);
      }
    }
  }
}

// ---------------- CSR mean aggregation (bf16 h -> bf16 mean) ----------------
// One wave per node. Edge indices loaded coalesced 64-wide, broadcast via
// v_readlane (uniform -> SGPR base); row gathers unrolled x8 so 8 independent
// 256B loads are in flight before the first vmcnt wait.
__global__ __launch_bounds__(256) void k_aggregate(
    const unsigned short* __restrict__ h, const int* __restrict__ offs,
    const int* __restrict__ counts, const int* __restrict__ esrc,
    unsigned short* __restrict__ mean)
{
  const int node = blockIdx.x*4 + (threadIdx.x >> 6);
  const int lane = threadIdx.x & 63;
  if(node >= N_NODES) return;
  const int beg = offs[node];
  const int deg = counts[node];
  const unsigned* hp = (const unsigned*)h;
  float a0 = 0.f, a1 = 0.f;
  for(int base = 0; base < deg; base += 64){
    const int rem = deg - base;
    const int cnt = rem < 64 ? rem : 64;
    const int myi = (lane < cnt) ? esrc[beg + base + lane] : 0;   // coalesced
    int e = 0;
    for(; e + 8 <= cnt; e += 8){
      unsigned v[8];
      #pragma unroll
      for(int u = 0; u < 8; u++){
        const int s = __builtin_amdgcn_readlane(myi, e + u);
        v[u] = hp[(size_t)s*64 + lane];
      }
      #pragma unroll
      for(int u = 0; u < 8; u++){
        a0 += bf2f((unsigned short)(v[u] & 0xffffu));
        a1 += bf2f((unsigned short)(v[u] >> 16));
      }
    }
    for(; e < cnt; e++){
      const int s = __builtin_amdgcn_readlane(myi, e);
      const unsigned vv = hp[(size_t)s*64 + lane];
      a0 += bf2f((unsigned short)(vv & 0xffffu));
      a1 += bf2f((unsigned short)(vv >> 16));
    }
  }
  const float inv = (deg > 0) ? (1.0f/(float)deg) : 0.f;
  a0 *= inv; a1 *= inv;
  unsigned o = ((unsigned)(unsigned short)f2bf(a1) << 16) | (unsigned)(unsigned short)f2bf(a0);
  ((unsigned*)mean)[(size_t)node*64 + lane] = o;
}

// ---------------- post: log_softmax(h @ W_post + b_post) ----------------
__global__ __launch_bounds__(256) void k_post(
    const unsigned short* __restrict__ h, const float* __restrict__ W,
    const float* __restrict__ b, float* __restrict__ out)
{
  __shared__ float wl[HID*NCLS];
  __shared__ float hs[4][HID];
  for(int i = threadIdx.x; i < HID*NCLS; i += 256) wl[i] = W[i];
  __syncthreads();
  const int wave = threadIdx.x >> 6, lane = threadIdx.x & 63;
  for(int row = blockIdx.x*4 + wave; row < N_NODES; row += gridDim.x*4){
    if(lane < 16){
      short8 v = *reinterpret_cast<const short8*>(h + (size_t)row*HID + lane*8);
      #pragma unroll
      for(int j = 0; j < 8; j++) hs[wave][lane*8 + j] = bf2f((unsigned short)v[j]);
    }
    __syncthreads();   // uniform trip counts: N % 4 == 0
    float acc;
    if(lane < NCLS){
      float s = b[lane];
      #pragma unroll 8
      for(int k = 0; k < HID; k++) s += hs[wave][k]*wl[k*NCLS + lane];
      acc = s;
    } else acc = -1e30f;
    float m = acc;
    #pragma unroll
    for(int o = 32; o > 0; o >>= 1) m = fmaxf(m, __shfl_xor(m, o));
    float ex = (lane < NCLS) ? expf(acc - m) : 0.f;
    float ssum = ex;
    #pragma unroll
    for(int o = 32; o > 0; o >>= 1) ssum += __shfl_xor(ssum, o);
    const float ls = logf(ssum);
    if(lane < NCLS) out[(size_t)row*NCLS + lane] = acc - m - ls;
    __syncthreads();
  }
}

extern "C" void kernel_launch(void* const* d_in, const int* in_sizes, int n_in,
                              void* d_out, int out_size, void* d_ws, size_t ws_size,
                              hipStream_t stream)
{
  const float* x      = (const float*)d_in[0];
  const int*   ei     = (const int*)  d_in[1];
  const float* W_pre  = (const float*)d_in[2];
  const float* b_pre  = (const float*)d_in[3];
  const float* Wl0    = (const float*)d_in[4];
  const float* bl0    = (const float*)d_in[5];
  const float* Wr0    = (const float*)d_in[6];
  const float* Wl1    = (const float*)d_in[7];
  const float* bl1    = (const float*)d_in[8];
  const float* Wr1    = (const float*)d_in[9];
  const float* W_post = (const float*)d_in[10];
  const float* b_post = (const float*)d_in[11];
  float* out = (float*)d_out;

  const int E = in_sizes[1] / 2;
  const int* src = ei;
  const int* dst = ei + E;

  char* ws = (char*)d_ws;
  size_t off = 0;
  auto alloc = [&](size_t bytes)->void*{
    void* p = ws + off;
    off += (bytes + 255) & ~(size_t)255;
    return p;
  };
  unsigned short* hA = (unsigned short*)alloc((size_t)N_NODES*HID*2);
  unsigned short* hB = (unsigned short*)alloc((size_t)N_NODES*HID*2);
  unsigned short* hM = (unsigned short*)alloc((size_t)N_NODES*HID*2);
  int* counts   = (int*)alloc((size_t)N_NODES*4);
  int* offs     = (int*)alloc((size_t)N_NODES*4);
  int* cursor   = (int*)alloc((size_t)N_NODES*4);
  int* esrc     = (int*)alloc((size_t)E*4);
  int* partials = (int*)alloc(1024);

  // ---- CSR build (amortized over both layers) ----
  k_zero<<<(N_NODES+255)/256, 256, 0, stream>>>(counts, N_NODES);
  k_count<<<(E+255)/256, 256, 0, stream>>>(dst, counts, E);
  const int nb = (N_NODES + SCAN_BLK - 1) / SCAN_BLK;   // 196
  k_scanA<<<nb, SCAN_BLK, 0, stream>>>(counts, offs, partials, N_NODES);
  k_scanB<<<1, 256, 0, stream>>>(partials, nb);
  k_scanC<<<nb, SCAN_BLK, 0, stream>>>(offs, partials, cursor, N_NODES);
  k_scatter<<<(E+255)/256, 256, 0, stream>>>(src, dst, cursor, esrc, E);

  // ---- pre linear ----
  k_gemm_pre<<<1563, 256, 0, stream>>>(x, W_pre, b_pre, hA);

  // ---- SAGE layer 0 ----
  k_aggregate<<<N_NODES/4, 256, 0, stream>>>(hA, offs, counts, esrc, hM);
  k_gemm_sage<<<1563, 256, 0, stream>>>(hM, hA, Wl0, bl0, Wr0, hB);

  // ---- SAGE layer 1 ----
  k_aggregate<<<N_NODES/4, 256, 0, stream>>>(hB, offs, counts, esrc, hM);
  k_gemm_sage<<<1563, 256, 0, stream>>>(hM, hB, Wl1, bl1, Wr1, hA);

  // ---- post linear + log_softmax ----
  k_post<<<6250, 256, 0, stream>>>(hA, W_post, b_post, out);
}

// Round 3
// 521.844 us; speedup vs baseline: 1.4455x; 1.0992x over previous
//
#include <hip/hip_runtime.h>
#include <hip/hip_bf16.h>
#include <math.h>

#define N_NODES 100000
#define IN_F 256
#define HID 128
#define NCLS 40

typedef __attribute__((ext_vector_type(8))) short short8;
typedef __attribute__((ext_vector_type(4))) float f32x4;

__device__ __forceinline__ short f2bf(float f){
  union { float f; unsigned u; } x; x.f = f;
  unsigned r = (x.u + 0x7fffu + ((x.u >> 16) & 1u)) >> 16;
  return (short)r;
}
__device__ __forceinline__ float bf2f(unsigned short u){
  union { unsigned u; float f; } x; x.u = ((unsigned)u) << 16;
  return x.f;
}

// ---------------- CSR build ----------------
__global__ void k_zero(int* p, int n){
  int i = blockIdx.x*blockDim.x + threadIdx.x;
  if(i < n) p[i] = 0;
}

// XCD-colored count: block's color = blockIdx%8 (round-robin XCD mapping).
// Each color only touches counts in its 12500-node range -> atomics stay in
// one XCD's L2. dst[] is re-read 8x (sequential, L3-resident, cheap).
__global__ __launch_bounds__(256) void k_count(const int* __restrict__ dst,
                                               int* __restrict__ counts, int e){
  const int color = blockIdx.x & 7;
  const int lo = color * (N_NODES/8), hi = lo + (N_NODES/8);
  const int stride = (gridDim.x >> 3) * 256;
  for(int i = (blockIdx.x >> 3)*256 + threadIdx.x; i < e; i += stride){
    const int d = dst[i];
    if(d >= lo && d < hi) atomicAdd(&counts[d], 1);
  }
}

#define SCAN_BLK 512
__global__ void k_scanA(const int* __restrict__ counts, int* __restrict__ offs,
                        int* __restrict__ partials, int n){
  __shared__ int s[SCAN_BLK];
  const int t = threadIdx.x;
  const int i = blockIdx.x*SCAN_BLK + t;
  int v = (i < n) ? counts[i] : 0;
  s[t] = v; __syncthreads();
  for(int d = 1; d < SCAN_BLK; d <<= 1){
    int add = (t >= d) ? s[t-d] : 0;
    __syncthreads();
    s[t] += add;
    __syncthreads();
  }
  if(i < n) offs[i] = s[t] - v;                 // block-local exclusive
  if(t == SCAN_BLK-1) partials[blockIdx.x] = s[t];
}

__global__ void k_scanB(int* partials, int n){
  __shared__ int s[256];
  const int t = threadIdx.x;
  int v = (t < n) ? partials[t] : 0;
  s[t] = v; __syncthreads();
  for(int d = 1; d < 256; d <<= 1){
    int add = (t >= d) ? s[t-d] : 0;
    __syncthreads();
    s[t] += add;
    __syncthreads();
  }
  if(t < n) partials[t] = s[t] - v;             // exclusive
}

__global__ void k_scanC(int* __restrict__ offs, const int* __restrict__ partials,
                        int* __restrict__ cursor, int n){
  int i = blockIdx.x*blockDim.x + threadIdx.x;
  if(i < n){
    int v = offs[i] + partials[blockIdx.x];
    offs[i] = v;
    cursor[i] = v;
  }
}

// XCD-colored scatter: color c handles dst in [c*12500,(c+1)*12500). Since offs
// is sorted by node, color c's esrc writes land in one contiguous ~800KB region
// owned by one XCD's L2 -> each dirty line flushed once (kills the 16x write
// amplification seen as WRITE_SIZE=105MB for a 6.4MB array).
__global__ __launch_bounds__(256) void k_scatter(const int* __restrict__ src,
                                                 const int* __restrict__ dst,
                                                 int* __restrict__ cursor,
                                                 int* __restrict__ esrc, int e){
  const int color = blockIdx.x & 7;
  const int lo = color * (N_NODES/8), hi = lo + (N_NODES/8);
  const int stride = (gridDim.x >> 3) * 256;
  for(int i = (blockIdx.x >> 3)*256 + threadIdx.x; i < e; i += stride){
    const int d = dst[i];
    if(d >= lo && d < hi){
      int pos = atomicAdd(&cursor[d], 1);
      esrc[pos] = src[i];
    }
  }
}

// ---------------- pre GEMM: h0 = x @ W_pre + b_pre  (f32 in, bf16 out) ----------------
__global__ __launch_bounds__(256) void k_gemm_pre(
    const float* __restrict__ x, const float* __restrict__ W,
    const float* __restrict__ b, unsigned short* __restrict__ out)
{
  __shared__ short wlds[8][8][64][8];   // [ct][kb][lane][j] : B-frag layout, 64 KiB
  const int t = threadIdx.x;
  for(int idx = t; idx < 8*8*64; idx += 256){
    const int ct = idx >> 9, kb = (idx >> 6) & 7, l = idx & 63;
    const int col = ct*16 + (l & 15);
    const int kbase = kb*32 + (l >> 4)*8;
    short8 v;
    #pragma unroll
    for(int j = 0; j < 8; j++) v[j] = f2bf(W[(size_t)(kbase+j)*HID + col]);
    *reinterpret_cast<short8*>(&wlds[ct][kb][l][0]) = v;
  }
  __syncthreads();
  const int wave = t >> 6, lane = t & 63;
  const int r_in = lane & 15, kg = lane >> 4;
  for(int tile = blockIdx.x*4 + wave; tile < N_NODES/16; tile += gridDim.x*4){
    const int row0 = tile*16;
    f32x4 acc[8];
    #pragma unroll
    for(int ct = 0; ct < 8; ct++) acc[ct] = (f32x4){0.f,0.f,0.f,0.f};
    #pragma unroll
    for(int kb = 0; kb < 8; kb++){
      const float* xp = x + (size_t)(row0 + r_in)*IN_F + kb*32 + kg*8;
      float4 xa = *reinterpret_cast<const float4*>(xp);
      float4 xb = *reinterpret_cast<const float4*>(xp + 4);
      short8 a;
      a[0]=f2bf(xa.x); a[1]=f2bf(xa.y); a[2]=f2bf(xa.z); a[3]=f2bf(xa.w);
      a[4]=f2bf(xb.x); a[5]=f2bf(xb.y); a[6]=f2bf(xb.z); a[7]=f2bf(xb.w);
      #pragma unroll
      for(int ct = 0; ct < 8; ct++){
        short8 bb = *reinterpret_cast<const short8*>(&wlds[ct][kb][lane][0]);
        acc[ct] = __builtin_amdgcn_mfma_f32_16x16x32_bf16(a, bb, acc[ct], 0, 0, 0);
      }
    }
    #pragma unroll
    for(int ct = 0; ct < 8; ct++){
      const int col = ct*16 + r_in;
      const float bias = b[col];
      #pragma unroll
      for(int i = 0; i < 4; i++){
        const int row = row0 + kg*4 + i;
        out[(size_t)row*HID + col] = (unsigned short)f2bf(acc[ct][i] + bias);
      }
    }
  }
}

// ------- sage GEMM: out = relu(mean @ Wl + bl + h @ Wr)  (bf16 in/out) -------
__global__ __launch_bounds__(256) void k_gemm_sage(
    const unsigned short* __restrict__ mean, const unsigned short* __restrict__ h,
    const float* __restrict__ Wl, const float* __restrict__ bl,
    const float* __restrict__ Wr, unsigned short* __restrict__ out)
{
  __shared__ short wlds[8][8][64][8];   // kb 0..3 -> Wl, 4..7 -> Wr
  const int t = threadIdx.x;
  for(int idx = t; idx < 8*8*64; idx += 256){
    const int ct = idx >> 9, kb = (idx >> 6) & 7, l = idx & 63;
    const float* Wsrc = (kb < 4) ? Wl : Wr;
    const int col = ct*16 + (l & 15);
    const int kbase = (kb & 3)*32 + (l >> 4)*8;
    short8 v;
    #pragma unroll
    for(int j = 0; j < 8; j++) v[j] = f2bf(Wsrc[(size_t)(kbase+j)*HID + col]);
    *reinterpret_cast<short8*>(&wlds[ct][kb][l][0]) = v;
  }
  __syncthreads();
  const int wave = t >> 6, lane = t & 63;
  const int r_in = lane & 15, kg = lane >> 4;
  for(int tile = blockIdx.x*4 + wave; tile < N_NODES/16; tile += gridDim.x*4){
    const int row0 = tile*16;
    f32x4 acc[8];
    #pragma unroll
    for(int ct = 0; ct < 8; ct++) acc[ct] = (f32x4){0.f,0.f,0.f,0.f};
    #pragma unroll
    for(int kb = 0; kb < 8; kb++){
      const unsigned short* in = (kb < 4) ? mean : h;
      const int koff = (kb & 3)*32 + kg*8;
      short8 a = *reinterpret_cast<const short8*>(in + (size_t)(row0 + r_in)*HID + koff);
      #pragma unroll
      for(int ct = 0; ct < 8; ct++){
        short8 bb = *reinterpret_cast<const short8*>(&wlds[ct][kb][lane][0]);
        acc[ct] = __builtin_amdgcn_mfma_f32_16x16x32_bf16(a, bb, acc[ct], 0, 0, 0);
      }
    }
    #pragma unroll
    for(int ct = 0; ct < 8; ct++){
      const int col = ct*16 + r_in;
      const float bias = bl[col];
      #pragma unroll
      for(int i = 0; i < 4; i++){
        const int row = row0 + kg*4 + i;
        float v = fmaxf(acc[ct][i] + bias, 0.f);
        out[(size_t)row*HID + col] = (unsigned short)f2bf(v);
      }
    }
  }
}

// ---------------- CSR mean aggregation (bf16 h -> bf16 mean) ----------------
// One wave per node. Edge indices loaded coalesced 64-wide, broadcast via
// v_readlane; row gathers unrolled x8 so 8 independent 256B loads are in
// flight before the first vmcnt wait.
__global__ __launch_bounds__(256) void k_aggregate(
    const unsigned short* __restrict__ h, const int* __restrict__ offs,
    const int* __restrict__ counts, const int* __restrict__ esrc,
    unsigned short* __restrict__ mean)
{
  const int node = blockIdx.x*4 + (threadIdx.x >> 6);
  const int lane = threadIdx.x & 63;
  if(node >= N_NODES) return;
  const int beg = offs[node];
  const int deg = counts[node];
  const unsigned* hp = (const unsigned*)h;
  float a0 = 0.f, a1 = 0.f;
  for(int base = 0; base < deg; base += 64){
    const int rem = deg - base;
    const int cnt = rem < 64 ? rem : 64;
    const int myi = (lane < cnt) ? esrc[beg + base + lane] : 0;   // coalesced
    int e = 0;
    for(; e + 8 <= cnt; e += 8){
      unsigned v[8];
      #pragma unroll
      for(int u = 0; u < 8; u++){
        const int s = __builtin_amdgcn_readlane(myi, e + u);
        v[u] = hp[(size_t)s*64 + lane];
      }
      #pragma unroll
      for(int u = 0; u < 8; u++){
        a0 += bf2f((unsigned short)(v[u] & 0xffffu));
        a1 += bf2f((unsigned short)(v[u] >> 16));
      }
    }
    for(; e < cnt; e++){
      const int s = __builtin_amdgcn_readlane(myi, e);
      const unsigned vv = hp[(size_t)s*64 + lane];
      a0 += bf2f((unsigned short)(vv & 0xffffu));
      a1 += bf2f((unsigned short)(vv >> 16));
    }
  }
  const float inv = (deg > 0) ? (1.0f/(float)deg) : 0.f;
  a0 *= inv; a1 *= inv;
  unsigned o = ((unsigned)(unsigned short)f2bf(a1) << 16) | (unsigned)(unsigned short)f2bf(a0);
  ((unsigned*)mean)[(size_t)node*64 + lane] = o;
}

// ---------------- post: log_softmax(h @ W_post + b_post) ----------------
__global__ __launch_bounds__(256) void k_post(
    const unsigned short* __restrict__ h, const float* __restrict__ W,
    const float* __restrict__ b, float* __restrict__ out)
{
  __shared__ float wl[HID*NCLS];
  __shared__ float hs[4][HID];
  for(int i = threadIdx.x; i < HID*NCLS; i += 256) wl[i] = W[i];
  __syncthreads();
  const int wave = threadIdx.x >> 6, lane = threadIdx.x & 63;
  for(int row = blockIdx.x*4 + wave; row < N_NODES; row += gridDim.x*4){
    if(lane < 16){
      short8 v = *reinterpret_cast<const short8*>(h + (size_t)row*HID + lane*8);
      #pragma unroll
      for(int j = 0; j < 8; j++) hs[wave][lane*8 + j] = bf2f((unsigned short)v[j]);
    }
    __syncthreads();   // uniform trip counts: N % 4 == 0
    float acc;
    if(lane < NCLS){
      float s = b[lane];
      #pragma unroll 8
      for(int k = 0; k < HID; k++) s += hs[wave][k]*wl[k*NCLS + lane];
      acc = s;
    } else acc = -1e30f;
    float m = acc;
    #pragma unroll
    for(int o = 32; o > 0; o >>= 1) m = fmaxf(m, __shfl_xor(m, o));
    float ex = (lane < NCLS) ? expf(acc - m) : 0.f;
    float ssum = ex;
    #pragma unroll
    for(int o = 32; o > 0; o >>= 1) ssum += __shfl_xor(ssum, o);
    const float ls = logf(ssum);
    if(lane < NCLS) out[(size_t)row*NCLS + lane] = acc - m - ls;
    __syncthreads();
  }
}

extern "C" void kernel_launch(void* const* d_in, const int* in_sizes, int n_in,
                              void* d_out, int out_size, void* d_ws, size_t ws_size,
                              hipStream_t stream)
{
  const float* x      = (const float*)d_in[0];
  const int*   ei     = (const int*)  d_in[1];
  const float* W_pre  = (const float*)d_in[2];
  const float* b_pre  = (const float*)d_in[3];
  const float* Wl0    = (const float*)d_in[4];
  const float* bl0    = (const float*)d_in[5];
  const float* Wr0    = (const float*)d_in[6];
  const float* Wl1    = (const float*)d_in[7];
  const float* bl1    = (const float*)d_in[8];
  const float* Wr1    = (const float*)d_in[9];
  const float* W_post = (const float*)d_in[10];
  const float* b_post = (const float*)d_in[11];
  float* out = (float*)d_out;

  const int E = in_sizes[1] / 2;
  const int* src = ei;
  const int* dst = ei + E;

  char* ws = (char*)d_ws;
  size_t off = 0;
  auto alloc = [&](size_t bytes)->void*{
    void* p = ws + off;
    off += (bytes + 255) & ~(size_t)255;
    return p;
  };
  unsigned short* hA = (unsigned short*)alloc((size_t)N_NODES*HID*2);
  unsigned short* hB = (unsigned short*)alloc((size_t)N_NODES*HID*2);
  unsigned short* hM = (unsigned short*)alloc((size_t)N_NODES*HID*2);
  int* counts   = (int*)alloc((size_t)N_NODES*4);
  int* offs     = (int*)alloc((size_t)N_NODES*4);
  int* cursor   = (int*)alloc((size_t)N_NODES*4);
  int* esrc     = (int*)alloc((size_t)E*4);
  int* partials = (int*)alloc(1024);

  // ---- CSR build (XCD-colored atomics/writes; amortized over both layers) ----
  k_zero<<<(N_NODES+255)/256, 256, 0, stream>>>(counts, N_NODES);
  k_count<<<2048, 256, 0, stream>>>(dst, counts, E);        // 256 chunks x 8 colors
  const int nb = (N_NODES + SCAN_BLK - 1) / SCAN_BLK;       // 196
  k_scanA<<<nb, SCAN_BLK, 0, stream>>>(counts, offs, partials, N_NODES);
  k_scanB<<<1, 256, 0, stream>>>(partials, nb);
  k_scanC<<<nb, SCAN_BLK, 0, stream>>>(offs, partials, cursor, N_NODES);
  k_scatter<<<2048, 256, 0, stream>>>(src, dst, cursor, esrc, E);

  // ---- pre linear ----
  k_gemm_pre<<<1563, 256, 0, stream>>>(x, W_pre, b_pre, hA);

  // ---- SAGE layer 0 ----
  k_aggregate<<<N_NODES/4, 256, 0, stream>>>(hA, offs, counts, esrc, hM);
  k_gemm_sage<<<1563, 256, 0, stream>>>(hM, hA, Wl0, bl0, Wr0, hB);

  // ---- SAGE layer 1 ----
  k_aggregate<<<N_NODES/4, 256, 0, stream>>>(hB, offs, counts, esrc, hM);
  k_gemm_sage<<<1563, 256, 0, stream>>>(hM, hB, Wl1, bl1, Wr1, hA);

  // ---- post linear + log_softmax ----
  k_post<<<6250, 256, 0, stream>>>(hA, W_post, b_post, out);
}

// Round 4
// 448.758 us; speedup vs baseline: 1.6810x; 1.1629x over previous
//
#include <hip/hip_runtime.h>
#include <hip/hip_bf16.h>
#include <math.h>

#define N_NODES 100000
#define IN_F 256
#define HID 128
#define NCLS 40

typedef __attribute__((ext_vector_type(8))) short short8;
typedef __attribute__((ext_vector_type(4))) float f32x4;

__device__ __forceinline__ short f2bf(float f){
  union { float f; unsigned u; } x; x.f = f;
  unsigned r = (x.u + 0x7fffu + ((x.u >> 16) & 1u)) >> 16;
  return (short)r;
}
__device__ __forceinline__ float bf2f(unsigned short u){
  union { unsigned u; float f; } x; x.u = ((unsigned)u) << 16;
  return x.f;
}

// ---------------- CSR build ----------------
__global__ void k_zero(int* p, int n){
  int i = blockIdx.x*blockDim.x + threadIdx.x;
  if(i < n) p[i] = 0;
}

// XCD-colored count: block's color = blockIdx%8 (round-robin XCD mapping).
__global__ __launch_bounds__(256) void k_count(const int* __restrict__ dst,
                                               int* __restrict__ counts, int e){
  const int color = blockIdx.x & 7;
  const int lo = color * (N_NODES/8), hi = lo + (N_NODES/8);
  const int stride = (gridDim.x >> 3) * 256;
  for(int i = (blockIdx.x >> 3)*256 + threadIdx.x; i < e; i += stride){
    const int d = dst[i];
    if(d >= lo && d < hi) atomicAdd(&counts[d], 1);
  }
}

#define SCAN_BLK 512
__global__ void k_scanA(const int* __restrict__ counts, int* __restrict__ offs,
                        int* __restrict__ partials, int n){
  __shared__ int s[SCAN_BLK];
  const int t = threadIdx.x;
  const int i = blockIdx.x*SCAN_BLK + t;
  int v = (i < n) ? counts[i] : 0;
  s[t] = v; __syncthreads();
  for(int d = 1; d < SCAN_BLK; d <<= 1){
    int add = (t >= d) ? s[t-d] : 0;
    __syncthreads();
    s[t] += add;
    __syncthreads();
  }
  if(i < n) offs[i] = s[t] - v;                 // block-local exclusive
  if(t == SCAN_BLK-1) partials[blockIdx.x] = s[t];
}

__global__ void k_scanB(int* partials, int n){
  __shared__ int s[256];
  const int t = threadIdx.x;
  int v = (t < n) ? partials[t] : 0;
  s[t] = v; __syncthreads();
  for(int d = 1; d < 256; d <<= 1){
    int add = (t >= d) ? s[t-d] : 0;
    __syncthreads();
    s[t] += add;
    __syncthreads();
  }
  if(t < n) partials[t] = s[t] - v;             // exclusive
}

__global__ void k_scanC(int* __restrict__ offs, const int* __restrict__ partials,
                        int* __restrict__ cursor, int n){
  int i = blockIdx.x*blockDim.x + threadIdx.x;
  if(i < n){
    int v = offs[i] + partials[blockIdx.x];
    offs[i] = v;
    cursor[i] = v;
  }
}

// XCD-colored scatter: color c handles dst in [c*12500,(c+1)*12500).
__global__ __launch_bounds__(256) void k_scatter(const int* __restrict__ src,
                                                 const int* __restrict__ dst,
                                                 int* __restrict__ cursor,
                                                 int* __restrict__ esrc, int e){
  const int color = blockIdx.x & 7;
  const int lo = color * (N_NODES/8), hi = lo + (N_NODES/8);
  const int stride = (gridDim.x >> 3) * 256;
  for(int i = (blockIdx.x >> 3)*256 + threadIdx.x; i < e; i += stride){
    const int d = dst[i];
    if(d >= lo && d < hi){
      int pos = atomicAdd(&cursor[d], 1);
      esrc[pos] = src[i];
    }
  }
}

// ---------------- pre GEMM: h0 = x @ W_pre + b_pre  (f32 in, bf16 out) ----------------
__global__ __launch_bounds__(256) void k_gemm_pre(
    const float* __restrict__ x, const float* __restrict__ W,
    const float* __restrict__ b, unsigned short* __restrict__ out)
{
  __shared__ short wlds[8][8][64][8];   // [ct][kb][lane][j] : B-frag layout, 64 KiB
  const int t = threadIdx.x;
  for(int idx = t; idx < 8*8*64; idx += 256){
    const int ct = idx >> 9, kb = (idx >> 6) & 7, l = idx & 63;
    const int col = ct*16 + (l & 15);
    const int kbase = kb*32 + (l >> 4)*8;
    short8 v;
    #pragma unroll
    for(int j = 0; j < 8; j++) v[j] = f2bf(W[(size_t)(kbase+j)*HID + col]);
    *reinterpret_cast<short8*>(&wlds[ct][kb][l][0]) = v;
  }
  __syncthreads();
  const int wave = t >> 6, lane = t & 63;
  const int r_in = lane & 15, kg = lane >> 4;
  for(int tile = blockIdx.x*4 + wave; tile < N_NODES/16; tile += gridDim.x*4){
    const int row0 = tile*16;
    f32x4 acc[8];
    #pragma unroll
    for(int ct = 0; ct < 8; ct++) acc[ct] = (f32x4){0.f,0.f,0.f,0.f};
    #pragma unroll
    for(int kb = 0; kb < 8; kb++){
      const float* xp = x + (size_t)(row0 + r_in)*IN_F + kb*32 + kg*8;
      float4 xa = *reinterpret_cast<const float4*>(xp);
      float4 xb = *reinterpret_cast<const float4*>(xp + 4);
      short8 a;
      a[0]=f2bf(xa.x); a[1]=f2bf(xa.y); a[2]=f2bf(xa.z); a[3]=f2bf(xa.w);
      a[4]=f2bf(xb.x); a[5]=f2bf(xb.y); a[6]=f2bf(xb.z); a[7]=f2bf(xb.w);
      #pragma unroll
      for(int ct = 0; ct < 8; ct++){
        short8 bb = *reinterpret_cast<const short8*>(&wlds[ct][kb][lane][0]);
        acc[ct] = __builtin_amdgcn_mfma_f32_16x16x32_bf16(a, bb, acc[ct], 0, 0, 0);
      }
    }
    #pragma unroll
    for(int ct = 0; ct < 8; ct++){
      const int col = ct*16 + r_in;
      const float bias = b[col];
      #pragma unroll
      for(int i = 0; i < 4; i++){
        const int row = row0 + kg*4 + i;
        out[(size_t)row*HID + col] = (unsigned short)f2bf(acc[ct][i] + bias);
      }
    }
  }
}

// ------- sage GEMM: out = relu(mean @ Wl + bl + h @ Wr)  (bf16 in/out) -------
__global__ __launch_bounds__(256) void k_gemm_sage(
    const unsigned short* __restrict__ mean, const unsigned short* __restrict__ h,
    const float* __restrict__ Wl, const float* __restrict__ bl,
    const float* __restrict__ Wr, unsigned short* __restrict__ out)
{
  __shared__ short wlds[8][8][64][8];   // kb 0..3 -> Wl, 4..7 -> Wr
  const int t = threadIdx.x;
  for(int idx = t; idx < 8*8*64; idx += 256){
    const int ct = idx >> 9, kb = (idx >> 6) & 7, l = idx & 63;
    const float* Wsrc = (kb < 4) ? Wl : Wr;
    const int col = ct*16 + (l & 15);
    const int kbase = (kb & 3)*32 + (l >> 4)*8;
    short8 v;
    #pragma unroll
    for(int j = 0; j < 8; j++) v[j] = f2bf(Wsrc[(size_t)(kbase+j)*HID + col]);
    *reinterpret_cast<short8*>(&wlds[ct][kb][l][0]) = v;
  }
  __syncthreads();
  const int wave = t >> 6, lane = t & 63;
  const int r_in = lane & 15, kg = lane >> 4;
  for(int tile = blockIdx.x*4 + wave; tile < N_NODES/16; tile += gridDim.x*4){
    const int row0 = tile*16;
    f32x4 acc[8];
    #pragma unroll
    for(int ct = 0; ct < 8; ct++) acc[ct] = (f32x4){0.f,0.f,0.f,0.f};
    #pragma unroll
    for(int kb = 0; kb < 8; kb++){
      const unsigned short* in = (kb < 4) ? mean : h;
      const int koff = (kb & 3)*32 + kg*8;
      short8 a = *reinterpret_cast<const short8*>(in + (size_t)(row0 + r_in)*HID + koff);
      #pragma unroll
      for(int ct = 0; ct < 8; ct++){
        short8 bb = *reinterpret_cast<const short8*>(&wlds[ct][kb][lane][0]);
        acc[ct] = __builtin_amdgcn_mfma_f32_16x16x32_bf16(a, bb, acc[ct], 0, 0, 0);
      }
    }
    #pragma unroll
    for(int ct = 0; ct < 8; ct++){
      const int col = ct*16 + r_in;
      const float bias = bl[col];
      #pragma unroll
      for(int i = 0; i < 4; i++){
        const int row = row0 + kg*4 + i;
        float v = fmaxf(acc[ct][i] + bias, 0.f);
        out[(size_t)row*HID + col] = (unsigned short)f2bf(v);
      }
    }
  }
}

// ---------------- CSR mean aggregation (bf16 h -> bf16 mean) ----------------
__global__ __launch_bounds__(256) void k_aggregate(
    const unsigned short* __restrict__ h, const int* __restrict__ offs,
    const int* __restrict__ counts, const int* __restrict__ esrc,
    unsigned short* __restrict__ mean)
{
  const int node = blockIdx.x*4 + (threadIdx.x >> 6);
  const int lane = threadIdx.x & 63;
  if(node >= N_NODES) return;
  const int beg = offs[node];
  const int deg = counts[node];
  const unsigned* hp = (const unsigned*)h;
  float a0 = 0.f, a1 = 0.f;
  for(int base = 0; base < deg; base += 64){
    const int rem = deg - base;
    const int cnt = rem < 64 ? rem : 64;
    const int myi = (lane < cnt) ? esrc[beg + base + lane] : 0;   // coalesced
    int e = 0;
    for(; e + 8 <= cnt; e += 8){
      unsigned v[8];
      #pragma unroll
      for(int u = 0; u < 8; u++){
        const int s = __builtin_amdgcn_readlane(myi, e + u);
        v[u] = hp[(size_t)s*64 + lane];
      }
      #pragma unroll
      for(int u = 0; u < 8; u++){
        a0 += bf2f((unsigned short)(v[u] & 0xffffu));
        a1 += bf2f((unsigned short)(v[u] >> 16));
      }
    }
    for(; e < cnt; e++){
      const int s = __builtin_amdgcn_readlane(myi, e);
      const unsigned vv = hp[(size_t)s*64 + lane];
      a0 += bf2f((unsigned short)(vv & 0xffffu));
      a1 += bf2f((unsigned short)(vv >> 16));
    }
  }
  const float inv = (deg > 0) ? (1.0f/(float)deg) : 0.f;
  a0 *= inv; a1 *= inv;
  unsigned o = ((unsigned)(unsigned short)f2bf(a1) << 16) | (unsigned)(unsigned short)f2bf(a0);
  ((unsigned*)mean)[(size_t)node*64 + lane] = o;
}

// ---------------- post: log_softmax(h @ W_post + b_post), MFMA ----------------
// M=100K, K=128, N=40 padded to 48 (3 col-tiles). Row r of the C tile lives in
// one 16-lane group (3 regs/lane) -> softmax reduce = 3 reg ops + 4 shfl_xor.
__global__ __launch_bounds__(256) void k_post(
    const unsigned short* __restrict__ h, const float* __restrict__ W,
    const float* __restrict__ b, float* __restrict__ out)
{
  __shared__ short wlds[3][4][64][8];   // [ct][kb][lane][j], 12 KiB
  __shared__ float bias_s[48];
  const int t = threadIdx.x;
  for(int idx = t; idx < 3*4*64; idx += 256){
    const int ct = idx >> 8, kb = (idx >> 6) & 3, l = idx & 63;
    const int col = ct*16 + (l & 15);
    const int kbase = kb*32 + (l >> 4)*8;
    short8 v;
    #pragma unroll
    for(int j = 0; j < 8; j++)
      v[j] = (col < NCLS) ? f2bf(W[(size_t)(kbase+j)*NCLS + col]) : (short)0;
    *reinterpret_cast<short8*>(&wlds[ct][kb][l][0]) = v;
  }
  if(t < 48) bias_s[t] = (t < NCLS) ? b[t] : -1e30f;
  __syncthreads();
  const int wave = t >> 6, lane = t & 63;
  const int r_in = lane & 15, kg = lane >> 4;
  for(int tile = blockIdx.x*4 + wave; tile < N_NODES/16; tile += gridDim.x*4){
    const int row0 = tile*16;
    f32x4 acc[3];
    #pragma unroll
    for(int ct = 0; ct < 3; ct++) acc[ct] = (f32x4){0.f,0.f,0.f,0.f};
    #pragma unroll
    for(int kb = 0; kb < 4; kb++){
      short8 a = *reinterpret_cast<const short8*>(h + (size_t)(row0 + r_in)*HID + kb*32 + kg*8);
      #pragma unroll
      for(int ct = 0; ct < 3; ct++){
        short8 bb = *reinterpret_cast<const short8*>(&wlds[ct][kb][lane][0]);
        acc[ct] = __builtin_amdgcn_mfma_f32_16x16x32_bf16(a, bb, acc[ct], 0, 0, 0);
      }
    }
    #pragma unroll
    for(int i = 0; i < 4; i++){
      float v0 = acc[0][i] + bias_s[r_in];
      float v1 = acc[1][i] + bias_s[16 + r_in];
      float v2 = acc[2][i] + bias_s[32 + r_in];
      float m = fmaxf(fmaxf(v0, v1), v2);
      #pragma unroll
      for(int o = 8; o > 0; o >>= 1) m = fmaxf(m, __shfl_xor(m, o));
      float s = expf(v0 - m) + expf(v1 - m) + expf(v2 - m);
      #pragma unroll
      for(int o = 8; o > 0; o >>= 1) s += __shfl_xor(s, o);
      const float ls = m + logf(s);
      const int row = row0 + kg*4 + i;
      float* op = out + (size_t)row*NCLS;
      op[r_in] = v0 - ls;
      op[16 + r_in] = v1 - ls;
      if(r_in < 8) op[32 + r_in] = v2 - ls;
    }
  }
}

extern "C" void kernel_launch(void* const* d_in, const int* in_sizes, int n_in,
                              void* d_out, int out_size, void* d_ws, size_t ws_size,
                              hipStream_t stream)
{
  const float* x      = (const float*)d_in[0];
  const int*   ei     = (const int*)  d_in[1];
  const float* W_pre  = (const float*)d_in[2];
  const float* b_pre  = (const float*)d_in[3];
  const float* Wl0    = (const float*)d_in[4];
  const float* bl0    = (const float*)d_in[5];
  const float* Wr0    = (const float*)d_in[6];
  const float* Wl1    = (const float*)d_in[7];
  const float* bl1    = (const float*)d_in[8];
  const float* Wr1    = (const float*)d_in[9];
  const float* W_post = (const float*)d_in[10];
  const float* b_post = (const float*)d_in[11];
  float* out = (float*)d_out;

  const int E = in_sizes[1] / 2;
  const int* src = ei;
  const int* dst = ei + E;

  char* ws = (char*)d_ws;
  size_t off = 0;
  auto alloc = [&](size_t bytes)->void*{
    void* p = ws + off;
    off += (bytes + 255) & ~(size_t)255;
    return p;
  };
  unsigned short* hA = (unsigned short*)alloc((size_t)N_NODES*HID*2);
  unsigned short* hB = (unsigned short*)alloc((size_t)N_NODES*HID*2);
  unsigned short* hM = (unsigned short*)alloc((size_t)N_NODES*HID*2);
  int* counts   = (int*)alloc((size_t)N_NODES*4);
  int* offs     = (int*)alloc((size_t)N_NODES*4);
  int* cursor   = (int*)alloc((size_t)N_NODES*4);
  int* esrc     = (int*)alloc((size_t)E*4);
  int* partials = (int*)alloc(1024);

  // ---- CSR build (XCD-colored atomics/writes; amortized over both layers) ----
  k_zero<<<(N_NODES+255)/256, 256, 0, stream>>>(counts, N_NODES);
  k_count<<<2048, 256, 0, stream>>>(dst, counts, E);        // 256 chunks x 8 colors
  const int nb = (N_NODES + SCAN_BLK - 1) / SCAN_BLK;       // 196
  k_scanA<<<nb, SCAN_BLK, 0, stream>>>(counts, offs, partials, N_NODES);
  k_scanB<<<1, 256, 0, stream>>>(partials, nb);
  k_scanC<<<nb, SCAN_BLK, 0, stream>>>(offs, partials, cursor, N_NODES);
  k_scatter<<<2048, 256, 0, stream>>>(src, dst, cursor, esrc, E);

  // ---- pre linear ----
  k_gemm_pre<<<1563, 256, 0, stream>>>(x, W_pre, b_pre, hA);

  // ---- SAGE layer 0 ----
  k_aggregate<<<N_NODES/4, 256, 0, stream>>>(hA, offs, counts, esrc, hM);
  k_gemm_sage<<<1563, 256, 0, stream>>>(hM, hA, Wl0, bl0, Wr0, hB);

  // ---- SAGE layer 1 ----
  k_aggregate<<<N_NODES/4, 256, 0, stream>>>(hB, offs, counts, esrc, hM);
  k_gemm_sage<<<1563, 256, 0, stream>>>(hM, hB, Wl1, bl1, Wr1, hA);

  // ---- post linear + log_softmax (MFMA) ----
  k_post<<<1563, 256, 0, stream>>>(hA, W_post, b_post, out);
}

// Round 5
// 428.060 us; speedup vs baseline: 1.7622x; 1.0484x over previous
//
#include <hip/hip_runtime.h>
#include <hip/hip_bf16.h>
#include <math.h>

#define N_NODES 100000
#define IN_F 256
#define HID 128
#define NCLS 40

typedef __attribute__((ext_vector_type(8))) short short8;
typedef __attribute__((ext_vector_type(4))) float f32x4;

__device__ __forceinline__ short f2bf(float f){
  union { float f; unsigned u; } x; x.f = f;
  unsigned r = (x.u + 0x7fffu + ((x.u >> 16) & 1u)) >> 16;
  return (short)r;
}
__device__ __forceinline__ float bf2f(unsigned short u){
  union { unsigned u; float f; } x; x.u = ((unsigned)u) << 16;
  return x.f;
}

// ---------------- CSR build ----------------
__global__ void k_zero(int* p, int n){
  int i = blockIdx.x*blockDim.x + threadIdx.x;
  if(i < n) p[i] = 0;
}

// XCD-colored count: block's color = blockIdx%8 (round-robin XCD mapping).
__global__ __launch_bounds__(256) void k_count(const int* __restrict__ dst,
                                               int* __restrict__ counts, int e){
  const int color = blockIdx.x & 7;
  const int lo = color * (N_NODES/8), hi = lo + (N_NODES/8);
  const int stride = (gridDim.x >> 3) * 256;
  for(int i = (blockIdx.x >> 3)*256 + threadIdx.x; i < e; i += stride){
    const int d = dst[i];
    if(d >= lo && d < hi) atomicAdd(&counts[d], 1);
  }
}

#define SCAN_BLK 512
__global__ void k_scanA(const int* __restrict__ counts, int* __restrict__ offs,
                        int* __restrict__ partials, int n){
  __shared__ int s[SCAN_BLK];
  const int t = threadIdx.x;
  const int i = blockIdx.x*SCAN_BLK + t;
  int v = (i < n) ? counts[i] : 0;
  s[t] = v; __syncthreads();
  for(int d = 1; d < SCAN_BLK; d <<= 1){
    int add = (t >= d) ? s[t-d] : 0;
    __syncthreads();
    s[t] += add;
    __syncthreads();
  }
  if(i < n) offs[i] = s[t] - v;                 // block-local exclusive
  if(t == SCAN_BLK-1) partials[blockIdx.x] = s[t];
}

__global__ void k_scanB(int* partials, int n){
  __shared__ int s[256];
  const int t = threadIdx.x;
  int v = (t < n) ? partials[t] : 0;
  s[t] = v; __syncthreads();
  for(int d = 1; d < 256; d <<= 1){
    int add = (t >= d) ? s[t-d] : 0;
    __syncthreads();
    s[t] += add;
    __syncthreads();
  }
  if(t < n) partials[t] = s[t] - v;             // exclusive
}

__global__ void k_scanC(int* __restrict__ offs, const int* __restrict__ partials,
                        int* __restrict__ cursor, int n){
  int i = blockIdx.x*blockDim.x + threadIdx.x;
  if(i < n){
    int v = offs[i] + partials[blockIdx.x];
    offs[i] = v;
    cursor[i] = v;
  }
}

// XCD-colored scatter: color c handles dst in [c*12500,(c+1)*12500).
__global__ __launch_bounds__(256) void k_scatter(const int* __restrict__ src,
                                                 const int* __restrict__ dst,
                                                 int* __restrict__ cursor,
                                                 int* __restrict__ esrc, int e){
  const int color = blockIdx.x & 7;
  const int lo = color * (N_NODES/8), hi = lo + (N_NODES/8);
  const int stride = (gridDim.x >> 3) * 256;
  for(int i = (blockIdx.x >> 3)*256 + threadIdx.x; i < e; i += stride){
    const int d = dst[i];
    if(d >= lo && d < hi){
      int pos = atomicAdd(&cursor[d], 1);
      esrc[pos] = src[i];
    }
  }
}

// ---------------- pre GEMM: h0 = x @ W_pre + b_pre  (f32 in, bf16 out) ----------------
// Grid sized to 512 (= 2 blocks/CU, the LDS cap) so each wave runs ~3 tiles and
// the 64KiB W-staging is amortized. Full 16-row A-tile prefetched into regs
// (16 independent dwordx4 in flight) before any convert/MFMA; at 8 waves/CU the
// VGPR budget is 256/wave so the +64 prefetch regs are occupancy-free.
__global__ __launch_bounds__(256) void k_gemm_pre(
    const float* __restrict__ x, const float* __restrict__ W,
    const float* __restrict__ b, unsigned short* __restrict__ out)
{
  __shared__ short wlds[8][8][64][8];   // [ct][kb][lane][j] : B-frag layout, 64 KiB
  const int t = threadIdx.x;
  for(int idx = t; idx < 8*8*64; idx += 256){
    const int ct = idx >> 9, kb = (idx >> 6) & 7, l = idx & 63;
    const int col = ct*16 + (l & 15);
    const int kbase = kb*32 + (l >> 4)*8;
    short8 v;
    #pragma unroll
    for(int j = 0; j < 8; j++) v[j] = f2bf(W[(size_t)(kbase+j)*HID + col]);
    *reinterpret_cast<short8*>(&wlds[ct][kb][l][0]) = v;
  }
  __syncthreads();
  const int wave = t >> 6, lane = t & 63;
  const int r_in = lane & 15, kg = lane >> 4;
  for(int tile = blockIdx.x*4 + wave; tile < N_NODES/16; tile += gridDim.x*4){
    const int row0 = tile*16;
    const float* xp = x + (size_t)(row0 + r_in)*IN_F + kg*8;
    float4 xa[8], xb[8];
    #pragma unroll
    for(int kb = 0; kb < 8; kb++){
      xa[kb] = *reinterpret_cast<const float4*>(xp + kb*32);
      xb[kb] = *reinterpret_cast<const float4*>(xp + kb*32 + 4);
    }
    f32x4 acc[8];
    #pragma unroll
    for(int ct = 0; ct < 8; ct++) acc[ct] = (f32x4){0.f,0.f,0.f,0.f};
    #pragma unroll
    for(int kb = 0; kb < 8; kb++){
      short8 a;
      a[0]=f2bf(xa[kb].x); a[1]=f2bf(xa[kb].y); a[2]=f2bf(xa[kb].z); a[3]=f2bf(xa[kb].w);
      a[4]=f2bf(xb[kb].x); a[5]=f2bf(xb[kb].y); a[6]=f2bf(xb[kb].z); a[7]=f2bf(xb[kb].w);
      #pragma unroll
      for(int ct = 0; ct < 8; ct++){
        short8 bb = *reinterpret_cast<const short8*>(&wlds[ct][kb][lane][0]);
        acc[ct] = __builtin_amdgcn_mfma_f32_16x16x32_bf16(a, bb, acc[ct], 0, 0, 0);
      }
    }
    #pragma unroll
    for(int ct = 0; ct < 8; ct++){
      const int col = ct*16 + r_in;
      const float bias = b[col];
      #pragma unroll
      for(int i = 0; i < 4; i++){
        const int row = row0 + kg*4 + i;
        out[(size_t)row*HID + col] = (unsigned short)f2bf(acc[ct][i] + bias);
      }
    }
  }
}

// ------- sage GEMM: out = relu(mean @ Wl + bl + h @ Wr)  (bf16 in/out) -------
__global__ __launch_bounds__(256) void k_gemm_sage(
    const unsigned short* __restrict__ mean, const unsigned short* __restrict__ h,
    const float* __restrict__ Wl, const float* __restrict__ bl,
    const float* __restrict__ Wr, unsigned short* __restrict__ out)
{
  __shared__ short wlds[8][8][64][8];   // kb 0..3 -> Wl, 4..7 -> Wr
  const int t = threadIdx.x;
  for(int idx = t; idx < 8*8*64; idx += 256){
    const int ct = idx >> 9, kb = (idx >> 6) & 7, l = idx & 63;
    const float* Wsrc = (kb < 4) ? Wl : Wr;
    const int col = ct*16 + (l & 15);
    const int kbase = (kb & 3)*32 + (l >> 4)*8;
    short8 v;
    #pragma unroll
    for(int j = 0; j < 8; j++) v[j] = f2bf(Wsrc[(size_t)(kbase+j)*HID + col]);
    *reinterpret_cast<short8*>(&wlds[ct][kb][l][0]) = v;
  }
  __syncthreads();
  const int wave = t >> 6, lane = t & 63;
  const int r_in = lane & 15, kg = lane >> 4;
  for(int tile = blockIdx.x*4 + wave; tile < N_NODES/16; tile += gridDim.x*4){
    const int row0 = tile*16;
    f32x4 acc[8];
    #pragma unroll
    for(int ct = 0; ct < 8; ct++) acc[ct] = (f32x4){0.f,0.f,0.f,0.f};
    #pragma unroll
    for(int kb = 0; kb < 8; kb++){
      const unsigned short* in = (kb < 4) ? mean : h;
      const int koff = (kb & 3)*32 + kg*8;
      short8 a = *reinterpret_cast<const short8*>(in + (size_t)(row0 + r_in)*HID + koff);
      #pragma unroll
      for(int ct = 0; ct < 8; ct++){
        short8 bb = *reinterpret_cast<const short8*>(&wlds[ct][kb][lane][0]);
        acc[ct] = __builtin_amdgcn_mfma_f32_16x16x32_bf16(a, bb, acc[ct], 0, 0, 0);
      }
    }
    #pragma unroll
    for(int ct = 0; ct < 8; ct++){
      const int col = ct*16 + r_in;
      const float bias = bl[col];
      #pragma unroll
      for(int i = 0; i < 4; i++){
        const int row = row0 + kg*4 + i;
        float v = fmaxf(acc[ct][i] + bias, 0.f);
        out[(size_t)row*HID + col] = (unsigned short)f2bf(v);
      }
    }
  }
}

// ---------------- CSR mean aggregation (bf16 h -> bf16 mean) ----------------
__global__ __launch_bounds__(256) void k_aggregate(
    const unsigned short* __restrict__ h, const int* __restrict__ offs,
    const int* __restrict__ counts, const int* __restrict__ esrc,
    unsigned short* __restrict__ mean)
{
  const int node = blockIdx.x*4 + (threadIdx.x >> 6);
  const int lane = threadIdx.x & 63;
  if(node >= N_NODES) return;
  const int beg = offs[node];
  const int deg = counts[node];
  const unsigned* hp = (const unsigned*)h;
  float a0 = 0.f, a1 = 0.f;
  for(int base = 0; base < deg; base += 64){
    const int rem = deg - base;
    const int cnt = rem < 64 ? rem : 64;
    const int myi = (lane < cnt) ? esrc[beg + base + lane] : 0;   // coalesced
    int e = 0;
    for(; e + 8 <= cnt; e += 8){
      unsigned v[8];
      #pragma unroll
      for(int u = 0; u < 8; u++){
        const int s = __builtin_amdgcn_readlane(myi, e + u);
        v[u] = hp[(size_t)s*64 + lane];
      }
      #pragma unroll
      for(int u = 0; u < 8; u++){
        a0 += bf2f((unsigned short)(v[u] & 0xffffu));
        a1 += bf2f((unsigned short)(v[u] >> 16));
      }
    }
    for(; e < cnt; e++){
      const int s = __builtin_amdgcn_readlane(myi, e);
      const unsigned vv = hp[(size_t)s*64 + lane];
      a0 += bf2f((unsigned short)(vv & 0xffffu));
      a1 += bf2f((unsigned short)(vv >> 16));
    }
  }
  const float inv = (deg > 0) ? (1.0f/(float)deg) : 0.f;
  a0 *= inv; a1 *= inv;
  unsigned o = ((unsigned)(unsigned short)f2bf(a1) << 16) | (unsigned)(unsigned short)f2bf(a0);
  ((unsigned*)mean)[(size_t)node*64 + lane] = o;
}

// ---------------- post: log_softmax(h @ W_post + b_post), MFMA ----------------
__global__ __launch_bounds__(256) void k_post(
    const unsigned short* __restrict__ h, const float* __restrict__ W,
    const float* __restrict__ b, float* __restrict__ out)
{
  __shared__ short wlds[3][4][64][8];   // [ct][kb][lane][j], 12 KiB
  __shared__ float bias_s[48];
  const int t = threadIdx.x;
  for(int idx = t; idx < 3*4*64; idx += 256){
    const int ct = idx >> 8, kb = (idx >> 6) & 3, l = idx & 63;
    const int col = ct*16 + (l & 15);
    const int kbase = kb*32 + (l >> 4)*8;
    short8 v;
    #pragma unroll
    for(int j = 0; j < 8; j++)
      v[j] = (col < NCLS) ? f2bf(W[(size_t)(kbase+j)*NCLS + col]) : (short)0;
    *reinterpret_cast<short8*>(&wlds[ct][kb][l][0]) = v;
  }
  if(t < 48) bias_s[t] = (t < NCLS) ? b[t] : -1e30f;
  __syncthreads();
  const int wave = t >> 6, lane = t & 63;
  const int r_in = lane & 15, kg = lane >> 4;
  for(int tile = blockIdx.x*4 + wave; tile < N_NODES/16; tile += gridDim.x*4){
    const int row0 = tile*16;
    f32x4 acc[3];
    #pragma unroll
    for(int ct = 0; ct < 3; ct++) acc[ct] = (f32x4){0.f,0.f,0.f,0.f};
    #pragma unroll
    for(int kb = 0; kb < 4; kb++){
      short8 a = *reinterpret_cast<const short8*>(h + (size_t)(row0 + r_in)*HID + kb*32 + kg*8);
      #pragma unroll
      for(int ct = 0; ct < 3; ct++){
        short8 bb = *reinterpret_cast<const short8*>(&wlds[ct][kb][lane][0]);
        acc[ct] = __builtin_amdgcn_mfma_f32_16x16x32_bf16(a, bb, acc[ct], 0, 0, 0);
      }
    }
    #pragma unroll
    for(int i = 0; i < 4; i++){
      float v0 = acc[0][i] + bias_s[r_in];
      float v1 = acc[1][i] + bias_s[16 + r_in];
      float v2 = acc[2][i] + bias_s[32 + r_in];
      float m = fmaxf(fmaxf(v0, v1), v2);
      #pragma unroll
      for(int o = 8; o > 0; o >>= 1) m = fmaxf(m, __shfl_xor(m, o));
      float s = expf(v0 - m) + expf(v1 - m) + expf(v2 - m);
      #pragma unroll
      for(int o = 8; o > 0; o >>= 1) s += __shfl_xor(s, o);
      const float ls = m + logf(s);
      const int row = row0 + kg*4 + i;
      float* op = out + (size_t)row*NCLS;
      op[r_in] = v0 - ls;
      op[16 + r_in] = v1 - ls;
      if(r_in < 8) op[32 + r_in] = v2 - ls;
    }
  }
}

extern "C" void kernel_launch(void* const* d_in, const int* in_sizes, int n_in,
                              void* d_out, int out_size, void* d_ws, size_t ws_size,
                              hipStream_t stream)
{
  const float* x      = (const float*)d_in[0];
  const int*   ei     = (const int*)  d_in[1];
  const float* W_pre  = (const float*)d_in[2];
  const float* b_pre  = (const float*)d_in[3];
  const float* Wl0    = (const float*)d_in[4];
  const float* bl0    = (const float*)d_in[5];
  const float* Wr0    = (const float*)d_in[6];
  const float* Wl1    = (const float*)d_in[7];
  const float* bl1    = (const float*)d_in[8];
  const float* Wr1    = (const float*)d_in[9];
  const float* W_post = (const float*)d_in[10];
  const float* b_post = (const float*)d_in[11];
  float* out = (float*)d_out;

  const int E = in_sizes[1] / 2;
  const int* src = ei;
  const int* dst = ei + E;

  char* ws = (char*)d_ws;
  size_t off = 0;
  auto alloc = [&](size_t bytes)->void*{
    void* p = ws + off;
    off += (bytes + 255) & ~(size_t)255;
    return p;
  };
  unsigned short* hA = (unsigned short*)alloc((size_t)N_NODES*HID*2);
  unsigned short* hB = (unsigned short*)alloc((size_t)N_NODES*HID*2);
  unsigned short* hM = (unsigned short*)alloc((size_t)N_NODES*HID*2);
  int* counts   = (int*)alloc((size_t)N_NODES*4);
  int* offs     = (int*)alloc((size_t)N_NODES*4);
  int* cursor   = (int*)alloc((size_t)N_NODES*4);
  int* esrc     = (int*)alloc((size_t)E*4);
  int* partials = (int*)alloc(1024);

  // ---- CSR build (XCD-colored atomics/writes; amortized over both layers) ----
  k_zero<<<(N_NODES+255)/256, 256, 0, stream>>>(counts, N_NODES);
  k_count<<<2048, 256, 0, stream>>>(dst, counts, E);        // 256 chunks x 8 colors
  const int nb = (N_NODES + SCAN_BLK - 1) / SCAN_BLK;       // 196
  k_scanA<<<nb, SCAN_BLK, 0, stream>>>(counts, offs, partials, N_NODES);
  k_scanB<<<1, 256, 0, stream>>>(partials, nb);
  k_scanC<<<nb, SCAN_BLK, 0, stream>>>(offs, partials, cursor, N_NODES);
  k_scatter<<<2048, 256, 0, stream>>>(src, dst, cursor, esrc, E);

  // ---- pre linear (512 blocks = 2/CU; W-staging amortized over ~12 tiles) ----
  k_gemm_pre<<<512, 256, 0, stream>>>(x, W_pre, b_pre, hA);

  // ---- SAGE layer 0 ----
  k_aggregate<<<N_NODES/4, 256, 0, stream>>>(hA, offs, counts, esrc, hM);
  k_gemm_sage<<<1563, 256, 0, stream>>>(hM, hA, Wl0, bl0, Wr0, hB);

  // ---- SAGE layer 1 ----
  k_aggregate<<<N_NODES/4, 256, 0, stream>>>(hB, offs, counts, esrc, hM);
  k_gemm_sage<<<1563, 256, 0, stream>>>(hM, hB, Wl1, bl1, Wr1, hA);

  // ---- post linear + log_softmax (MFMA) ----
  k_post<<<1563, 256, 0, stream>>>(hA, W_post, b_post, out);
}